// Round 1
// baseline (9052.103 us; speedup 1.0000x reference)
//
#include <hip/hip_runtime.h>

#define NF_ATOM 9
#define NF_BOND 3
#define DD 128
#define HH 256
#define NLAYER 5

// ---------- atom encoder: h[n] = sum_f atom_emb[f][x[n,f]] ----------
__global__ __launch_bounds__(256) void k_atom(const int* __restrict__ x,
        const float* __restrict__ emb, float* __restrict__ h, int N) {
    int gid = blockIdx.x * 256 + threadIdx.x;
    int n = gid >> 5;
    if (n >= N) return;
    int c = (gid & 31) << 2;
    const int* xr = x + n * NF_ATOM;
    float4 acc = make_float4(0.f, 0.f, 0.f, 0.f);
#pragma unroll
    for (int f = 0; f < NF_ATOM; ++f) {
        int idx = xr[f];
        float4 v = *(const float4*)(emb + ((size_t)(f * 120 + idx) * DD) + c);
        acc.x += v.x; acc.y += v.y; acc.z += v.z; acc.w += v.w;
    }
    *(float4*)(h + (size_t)n * DD + c) = acc;
}

// ---------- edge: aggr[dst] += relu(h[src] + bond_embed(e)) ----------
__global__ __launch_bounds__(256) void k_edge(const int* __restrict__ ei,
        const int* __restrict__ ea, const float* __restrict__ bemb,
        const float* __restrict__ h, float* __restrict__ aggr, int E) {
    int gid = blockIdx.x * 256 + threadIdx.x;
    int e = gid >> 5;
    if (e >= E) return;
    int c = (gid & 31) << 2;
    int src = ei[e];
    int dst = ei[E + e];
    int a0 = ea[e * 3 + 0], a1 = ea[e * 3 + 1], a2 = ea[e * 3 + 2];
    float4 v0 = *(const float4*)(bemb + (size_t)(0 * 6 + a0) * DD + c);
    float4 v1 = *(const float4*)(bemb + (size_t)(1 * 6 + a1) * DD + c);
    float4 v2 = *(const float4*)(bemb + (size_t)(2 * 6 + a2) * DD + c);
    float4 hv = *(const float4*)(h + (size_t)src * DD + c);
    float m0 = fmaxf(hv.x + v0.x + v1.x + v2.x, 0.f);
    float m1 = fmaxf(hv.y + v0.y + v1.y + v2.y, 0.f);
    float m2 = fmaxf(hv.z + v0.z + v1.z + v2.z, 0.f);
    float m3 = fmaxf(hv.w + v0.w + v1.w + v2.w, 0.f);
    float* dp = aggr + (size_t)dst * DD + c;
    atomicAdd(dp + 0, m0);
    atomicAdd(dp + 1, m1);
    atomicAdd(dp + 2, m2);
    atomicAdd(dp + 3, m3);
}

// ---------- GEMM1: y1 = ((1+eps)*h + aggr) @ W1 + b1, + BN partial sums ----------
__global__ __launch_bounds__(256) void k_gemm1(const float* __restrict__ h,
        const float* __restrict__ aggr, const float* __restrict__ W,
        const float* __restrict__ bias, const float* __restrict__ epsv, int l,
        float* __restrict__ y1, float* __restrict__ stats, int N) {
    __shared__ float zt[64 * 128];   // 32KB: z tile (rows x K)
    __shared__ float wt[32 * 256];   // 32KB: W chunk (k x cols)
    int tid = threadIdx.x;
    int row0 = blockIdx.x * 64;
    float ep = 1.0f + epsv[l];
#pragma unroll
    for (int i = 0; i < 8; ++i) {
        int elem = (i * 256 + tid) * 4;      // 0..8191
        int r = elem >> 7;
        float4 z = make_float4(0.f, 0.f, 0.f, 0.f);
        if (row0 + r < N) {
            float4 hv = *(const float4*)(h + (size_t)row0 * DD + elem);
            float4 av = *(const float4*)(aggr + (size_t)row0 * DD + elem);
            z.x = ep * hv.x + av.x; z.y = ep * hv.y + av.y;
            z.z = ep * hv.z + av.z; z.w = ep * hv.w + av.w;
        }
        *(float4*)(zt + elem) = z;
    }
    int wave = tid >> 6, lane = tid & 63;
    int c4 = lane << 2;
    float acc[16][4];
#pragma unroll
    for (int r = 0; r < 16; ++r) { acc[r][0] = acc[r][1] = acc[r][2] = acc[r][3] = 0.f; }
    const float* zrow = zt + wave * 16 * DD;
    for (int kc = 0; kc < 4; ++kc) {
        __syncthreads();
#pragma unroll
        for (int i = 0; i < 8; ++i) {
            int elem = (i * 256 + tid) * 4;
            *(float4*)(wt + elem) = *(const float4*)(W + (size_t)kc * 32 * HH + elem);
        }
        __syncthreads();
#pragma unroll
        for (int k4 = 0; k4 < 32; k4 += 4) {
            float4 w0 = *(const float4*)(wt + (k4 + 0) * HH + c4);
            float4 w1 = *(const float4*)(wt + (k4 + 1) * HH + c4);
            float4 w2 = *(const float4*)(wt + (k4 + 2) * HH + c4);
            float4 w3 = *(const float4*)(wt + (k4 + 3) * HH + c4);
#pragma unroll
            for (int r = 0; r < 16; ++r) {
                float4 z4 = *(const float4*)(zrow + r * DD + kc * 32 + k4);
                acc[r][0] += z4.x * w0.x + z4.y * w1.x + z4.z * w2.x + z4.w * w3.x;
                acc[r][1] += z4.x * w0.y + z4.y * w1.y + z4.z * w2.y + z4.w * w3.y;
                acc[r][2] += z4.x * w0.z + z4.y * w1.z + z4.z * w2.z + z4.w * w3.z;
                acc[r][3] += z4.x * w0.w + z4.y * w1.w + z4.z * w2.w + z4.w * w3.w;
            }
        }
    }
    float4 bv = *(const float4*)(bias + c4);
    float s0 = 0, s1 = 0, s2 = 0, s3 = 0, q0 = 0, q1 = 0, q2 = 0, q3 = 0;
#pragma unroll
    for (int r = 0; r < 16; ++r) {
        int row = row0 + wave * 16 + r;
        float a0 = acc[r][0] + bv.x;
        float a1 = acc[r][1] + bv.y;
        float a2 = acc[r][2] + bv.z;
        float a3 = acc[r][3] + bv.w;
        if (row < N) {
            float4 o = make_float4(a0, a1, a2, a3);
            *(float4*)(y1 + (size_t)row * HH + c4) = o;
            s0 += a0; s1 += a1; s2 += a2; s3 += a3;
            q0 += a0 * a0; q1 += a1 * a1; q2 += a2 * a2; q3 += a3 * a3;
        }
    }
    __syncthreads();
    float* red = zt;   // reuse: 4 waves * 64 lanes * 8 floats = 8KB
    float* rp = red + (wave * 64 + lane) * 8;
    rp[0] = s0; rp[1] = s1; rp[2] = s2; rp[3] = s3;
    rp[4] = q0; rp[5] = q1; rp[6] = q2; rp[7] = q3;
    __syncthreads();
    if (wave == 0) {
        float t[8];
#pragma unroll
        for (int j = 0; j < 8; ++j)
            t[j] = red[(0 * 64 + lane) * 8 + j] + red[(1 * 64 + lane) * 8 + j] +
                   red[(2 * 64 + lane) * 8 + j] + red[(3 * 64 + lane) * 8 + j];
#pragma unroll
        for (int j = 0; j < 4; ++j) {
            atomicAdd(stats + c4 + j, t[j]);
            atomicAdd(stats + HH + c4 + j, t[4 + j]);
        }
    }
}

// ---------- GEMM2: y2 = relu(bn1(y1)) @ W2 + b2, + BN2 partial sums ----------
__global__ __launch_bounds__(256) void k_gemm2(const float* __restrict__ y1,
        const float* __restrict__ W, const float* __restrict__ bias,
        const float* __restrict__ sc1, const float* __restrict__ sh1,
        float* __restrict__ y2, float* __restrict__ stats2, int N) {
    __shared__ float at[64 * 64];    // 16KB
    __shared__ float wt[64 * 128];   // 32KB
    int tid = threadIdx.x;
    int row0 = blockIdx.x * 64;
    int wave = tid >> 6, lane = tid & 63;
    int sub = lane >> 5, li = lane & 31;
    int c4 = li << 2;
    int rbase = wave * 16 + sub * 8;
    float acc[8][4];
#pragma unroll
    for (int r = 0; r < 8; ++r) { acc[r][0] = acc[r][1] = acc[r][2] = acc[r][3] = 0.f; }
    for (int kc = 0; kc < 4; ++kc) {
        __syncthreads();
#pragma unroll
        for (int i = 0; i < 4; ++i) {
            int elem = (i * 256 + tid) * 4;   // 0..4095
            int r = elem >> 6, co = elem & 63;
            int col = kc * 64 + co;
            float4 v = make_float4(0.f, 0.f, 0.f, 0.f);
            if (row0 + r < N) {
                float4 u = *(const float4*)(y1 + (size_t)(row0 + r) * HH + col);
                float4 s = *(const float4*)(sc1 + col);
                float4 t = *(const float4*)(sh1 + col);
                v.x = fmaxf(u.x * s.x + t.x, 0.f);
                v.y = fmaxf(u.y * s.y + t.y, 0.f);
                v.z = fmaxf(u.z * s.z + t.z, 0.f);
                v.w = fmaxf(u.w * s.w + t.w, 0.f);
            }
            *(float4*)(at + elem) = v;
        }
#pragma unroll
        for (int i = 0; i < 8; ++i) {
            int elem = (i * 256 + tid) * 4;
            *(float4*)(wt + elem) = *(const float4*)(W + (size_t)kc * 64 * DD + elem);
        }
        __syncthreads();
#pragma unroll
        for (int k4 = 0; k4 < 64; k4 += 4) {
            float4 w0 = *(const float4*)(wt + (k4 + 0) * DD + c4);
            float4 w1 = *(const float4*)(wt + (k4 + 1) * DD + c4);
            float4 w2 = *(const float4*)(wt + (k4 + 2) * DD + c4);
            float4 w3 = *(const float4*)(wt + (k4 + 3) * DD + c4);
#pragma unroll
            for (int r = 0; r < 8; ++r) {
                float4 z4 = *(const float4*)(at + (rbase + r) * 64 + k4);
                acc[r][0] += z4.x * w0.x + z4.y * w1.x + z4.z * w2.x + z4.w * w3.x;
                acc[r][1] += z4.x * w0.y + z4.y * w1.y + z4.z * w2.y + z4.w * w3.y;
                acc[r][2] += z4.x * w0.z + z4.y * w1.z + z4.z * w2.z + z4.w * w3.z;
                acc[r][3] += z4.x * w0.w + z4.y * w1.w + z4.z * w2.w + z4.w * w3.w;
            }
        }
    }
    float4 bv = *(const float4*)(bias + c4);
    float s0 = 0, s1 = 0, s2 = 0, s3 = 0, q0 = 0, q1 = 0, q2 = 0, q3 = 0;
#pragma unroll
    for (int r = 0; r < 8; ++r) {
        int row = row0 + rbase + r;
        float a0 = acc[r][0] + bv.x;
        float a1 = acc[r][1] + bv.y;
        float a2 = acc[r][2] + bv.z;
        float a3 = acc[r][3] + bv.w;
        if (row < N) {
            float4 o = make_float4(a0, a1, a2, a3);
            *(float4*)(y2 + (size_t)row * DD + c4) = o;
            s0 += a0; s1 += a1; s2 += a2; s3 += a3;
            q0 += a0 * a0; q1 += a1 * a1; q2 += a2 * a2; q3 += a3 * a3;
        }
    }
    __syncthreads();
    float* red = at;   // 8 groups * 32 * 8 = 8KB
    int g = wave * 2 + sub;
    float* rp = red + (g * 32 + li) * 8;
    rp[0] = s0; rp[1] = s1; rp[2] = s2; rp[3] = s3;
    rp[4] = q0; rp[5] = q1; rp[6] = q2; rp[7] = q3;
    __syncthreads();
    if (tid < 32) {
        float t[8] = {0, 0, 0, 0, 0, 0, 0, 0};
#pragma unroll
        for (int gg = 0; gg < 8; ++gg)
#pragma unroll
            for (int j = 0; j < 8; ++j)
                t[j] += red[(gg * 32 + tid) * 8 + j];
#pragma unroll
        for (int j = 0; j < 4; ++j) {
            atomicAdd(stats2 + tid * 4 + j, t[j]);
            atomicAdd(stats2 + DD + tid * 4 + j, t[4 + j]);
        }
    }
}

// ---------- finalize BN: scale = g*rsqrt(var+eps), shift = b - mu*scale ----------
__global__ void k_fin(const float* __restrict__ stats, const float* __restrict__ g,
        const float* __restrict__ b, float* __restrict__ scale, float* __restrict__ shift,
        int C, float invN) {
    int t = threadIdx.x;
    if (t >= C) return;
    float mu = stats[t] * invN;
    float var = stats[C + t] * invN - mu * mu;
    float rs = rsqrtf(var + 1e-5f);
    float sc = g[t] * rs;
    scale[t] = sc;
    shift[t] = b[t] - mu * sc;
}

// ---------- apply BN2 + relu -> h ----------
__global__ __launch_bounds__(256) void k_bnapply(const float* __restrict__ y2,
        const float* __restrict__ scale, const float* __restrict__ shift,
        float* __restrict__ out, int N) {
    size_t gid = (size_t)blockIdx.x * 256 + threadIdx.x;
    size_t base = gid * 4;
    if (base >= (size_t)N * DD) return;
    int c = (int)(base & (DD - 1));
    float4 v = *(const float4*)(y2 + base);
    float4 s = *(const float4*)(scale + c);
    float4 t = *(const float4*)(shift + c);
    float4 o;
    o.x = fmaxf(v.x * s.x + t.x, 0.f);
    o.y = fmaxf(v.y * s.y + t.y, 0.f);
    o.z = fmaxf(v.z * s.z + t.z, 0.f);
    o.w = fmaxf(v.w * s.w + t.w, 0.f);
    *(float4*)(out + base) = o;
}

extern "C" void kernel_launch(void* const* d_in, const int* in_sizes, int n_in,
                              void* d_out, int out_size, void* d_ws, size_t ws_size,
                              hipStream_t stream) {
    const int* x = (const int*)d_in[0];
    const int* ei = (const int*)d_in[1];
    const int* ea = (const int*)d_in[2];
    const float* atom_emb = (const float*)d_in[3];
    const float* bond_emb = (const float*)d_in[4];
    const float* W1 = (const float*)d_in[5];
    const float* b1 = (const float*)d_in[6];
    const float* bn1_g = (const float*)d_in[7];
    const float* bn1_b = (const float*)d_in[8];
    const float* W2 = (const float*)d_in[9];
    const float* b2 = (const float*)d_in[10];
    const float* epsv = (const float*)d_in[11];
    const float* obn_g = (const float*)d_in[12];
    const float* obn_b = (const float*)d_in[13];
    int N = in_sizes[0] / NF_ATOM;
    int E = in_sizes[1] / 2;

    float* h = (float*)d_out;                 // h lives in d_out (N*128)
    float* ws = (float*)d_ws;
    float* aggr = ws;                         // N*128 (reused as y2)
    float* y1 = ws + (size_t)N * DD;          // N*256
    float* st = y1 + (size_t)N * HH;          // stats: 1536 floats
    float* sum1 = st;                         // 256 sums + 256 sq
    float* sc1 = st + 512;
    float* sh1 = st + 768;
    float* sum2 = st + 1024;                  // 128 sums + 128 sq
    float* sc2 = st + 1280;
    float* sh2 = st + 1408;
    float invN = 1.0f / (float)N;

    k_atom<<<(N * 32 + 255) / 256, 256, 0, stream>>>(x, atom_emb, h, N);
    int gb = (N + 63) / 64;
    for (int l = 0; l < NLAYER; ++l) {
        hipMemsetAsync(aggr, 0, (size_t)N * DD * sizeof(float), stream);
        hipMemsetAsync(st, 0, 1536 * sizeof(float), stream);
        k_edge<<<(E * 32 + 255) / 256, 256, 0, stream>>>(ei, ea,
                bond_emb + (size_t)l * NF_BOND * 6 * DD, h, aggr, E);
        k_gemm1<<<gb, 256, 0, stream>>>(h, aggr, W1 + (size_t)l * DD * HH,
                b1 + l * HH, epsv, l, y1, sum1, N);
        k_fin<<<1, 256, 0, stream>>>(sum1, bn1_g + l * HH, bn1_b + l * HH, sc1, sh1, HH, invN);
        k_gemm2<<<gb, 256, 0, stream>>>(y1, W2 + (size_t)l * HH * DD, b2 + l * DD,
                sc1, sh1, aggr, sum2, N);
        k_fin<<<1, 128, 0, stream>>>(sum2, obn_g + l * DD, obn_b + l * DD, sc2, sh2, DD, invN);
        k_bnapply<<<(int)(((size_t)N * DD / 4 + 255) / 256), 256, 0, stream>>>(aggr, sc2, sh2, h, N);
    }
}

// Round 2
// 1679.655 us; speedup vs baseline: 5.3893x; 5.3893x over previous
//
#include <hip/hip_runtime.h>

#define NF_ATOM 9
#define NF_BOND 3
#define DD 128
#define HH 256
#define NLAYER 5

typedef float fv4 __attribute__((ext_vector_type(4)));
typedef __bf16 bfv8 __attribute__((ext_vector_type(8)));
typedef unsigned int uv4 __attribute__((ext_vector_type(4)));

__device__ inline unsigned short f2bf(float f) {
    unsigned int u = __builtin_bit_cast(unsigned int, f);
    u = u + 0x7FFFu + ((u >> 16) & 1u);
    return (unsigned short)(u >> 16);
}
__device__ inline float bf2f(unsigned short s) {
    unsigned int u = ((unsigned int)s) << 16;
    return __builtin_bit_cast(float, u);
}

// ---------- atom encoder ----------
__global__ __launch_bounds__(256) void k_atom(const int* __restrict__ x,
        const float* __restrict__ emb, float* __restrict__ h, int N) {
    int gid = blockIdx.x * 256 + threadIdx.x;
    int n = gid >> 5;
    if (n >= N) return;
    int c = (gid & 31) << 2;
    const int* xr = x + n * NF_ATOM;
    float4 acc = make_float4(0.f, 0.f, 0.f, 0.f);
#pragma unroll
    for (int f = 0; f < NF_ATOM; ++f) {
        int idx = xr[f];
        float4 v = *(const float4*)(emb + ((size_t)(f * 120 + idx) * DD) + c);
        acc.x += v.x; acc.y += v.y; acc.z += v.z; acc.w += v.w;
    }
    *(float4*)(h + (size_t)n * DD + c) = acc;
}

// ---------- weight convert: f32 [K][N] -> bf16 chunk-major [kc][n][32] ----------
__global__ __launch_bounds__(256) void k_wconv(const float* __restrict__ W1,
        const float* __restrict__ W2, unsigned short* __restrict__ W1t,
        unsigned short* __restrict__ W2t) {
    int id = blockIdx.x * 256 + threadIdx.x;
    const int T1 = NLAYER * 4 * 256 * 32;      // 163840
    if (id < T1) {
        int k = id & 31, n = (id >> 5) & 255, kc = (id >> 13) & 3, l = id >> 15;
        W1t[id] = f2bf(W1[((size_t)(l * 128 + kc * 32 + k)) * 256 + n]);
    } else {
        int id2 = id - T1;
        if (id2 >= NLAYER * 8 * 128 * 32) return;
        int k = id2 & 31, n = (id2 >> 5) & 127, kc = (id2 >> 12) & 7, l = id2 >> 15;
        W2t[id2] = f2bf(W2[((size_t)(l * 256 + kc * 32 + k)) * 128 + n]);
    }
}

// ---------- CSR build ----------
__global__ __launch_bounds__(256) void k_deg(const int* __restrict__ ei, int* __restrict__ deg, int E) {
    int e = blockIdx.x * 256 + threadIdx.x;
    if (e < E) atomicAdd(&deg[ei[E + e]], 1);
}
__global__ __launch_bounds__(256) void k_bsum(const int* __restrict__ deg, int* __restrict__ bsum, int N) {
    __shared__ int red[256];
    int t = threadIdx.x, b = blockIdx.x;
    int i0 = b * 1024 + t * 4;
    int s = 0;
#pragma unroll
    for (int j = 0; j < 4; ++j) if (i0 + j < N) s += deg[i0 + j];
    red[t] = s; __syncthreads();
    for (int off = 128; off > 0; off >>= 1) {
        if (t < off) red[t] += red[t + off];
        __syncthreads();
    }
    if (t == 0) bsum[b] = red[0];
}
__global__ __launch_bounds__(256) void k_bscan(const int* __restrict__ bsum, int* __restrict__ boff, int nb) {
    __shared__ int ts[256];
    int t = threadIdx.x;
    int v = (t < nb) ? bsum[t] : 0;
    ts[t] = v; __syncthreads();
    for (int off = 1; off < 256; off <<= 1) {
        int u = (t >= off) ? ts[t - off] : 0;
        __syncthreads();
        ts[t] += u;
        __syncthreads();
    }
    if (t < nb) boff[t] = ts[t] - v;   // exclusive
}
__global__ __launch_bounds__(256) void k_csr(const int* __restrict__ deg, const int* __restrict__ boff,
        int* __restrict__ rs, int* __restrict__ cur, int N, int E) {
    __shared__ int ts[256];
    int t = threadIdx.x, b = blockIdx.x;
    int i0 = b * 1024 + t * 4;
    int d[4];
#pragma unroll
    for (int j = 0; j < 4; ++j) d[j] = (i0 + j < N) ? deg[i0 + j] : 0;
    int tsum = d[0] + d[1] + d[2] + d[3];
    ts[t] = tsum; __syncthreads();
    for (int off = 1; off < 256; off <<= 1) {
        int u = (t >= off) ? ts[t - off] : 0;
        __syncthreads();
        ts[t] += u;
        __syncthreads();
    }
    int base = boff[b] + ts[t] - tsum;
    int p = 0;
#pragma unroll
    for (int j = 0; j < 4; ++j) {
        int dj = d[j];
        if (i0 + j < N) { rs[i0 + j] = base + p; cur[i0 + j] = base + p; }
        p += dj;
    }
    if (b == 0 && t == 0) rs[N] = E;
}
__global__ __launch_bounds__(256) void k_scatter(const int* __restrict__ ei, int* __restrict__ cur,
        int* __restrict__ elist, int E) {
    int e = blockIdx.x * 256 + threadIdx.x;
    if (e < E) {
        int pos = atomicAdd(&cur[ei[E + e]], 1);
        elist[pos] = e;
    }
}

// ---------- gather aggregation ----------
__global__ __launch_bounds__(256) void k_aggr(const int* __restrict__ rs, const int* __restrict__ elist,
        const int* __restrict__ ei, const int* __restrict__ ea, const float* __restrict__ bemb,
        const float* __restrict__ h, float* __restrict__ aggr, int N, int E) {
    int gid = blockIdx.x * 256 + threadIdx.x;
    int n = gid >> 5;
    if (n >= N) return;
    int c = (gid & 31) << 2;
    int p0 = rs[n], p1 = rs[n + 1];
    float4 acc = make_float4(0.f, 0.f, 0.f, 0.f);
    for (int p = p0; p < p1; ++p) {
        int eid = elist[p];
        int src = ei[eid];
        int a0 = ea[eid * 3 + 0], a1 = ea[eid * 3 + 1], a2 = ea[eid * 3 + 2];
        float4 v0 = *(const float4*)(bemb + (size_t)(0 * 6 + a0) * DD + c);
        float4 v1 = *(const float4*)(bemb + (size_t)(1 * 6 + a1) * DD + c);
        float4 v2 = *(const float4*)(bemb + (size_t)(2 * 6 + a2) * DD + c);
        float4 hv = *(const float4*)(h + (size_t)src * DD + c);
        acc.x += fmaxf(hv.x + v0.x + v1.x + v2.x, 0.f);
        acc.y += fmaxf(hv.y + v0.y + v1.y + v2.y, 0.f);
        acc.z += fmaxf(hv.z + v0.z + v1.z + v2.z, 0.f);
        acc.w += fmaxf(hv.w + v0.w + v1.w + v2.w, 0.f);
    }
    *(float4*)(aggr + (size_t)n * DD + c) = acc;
}

// ---------- GEMM1 (MFMA): y1_bf16 = z @ W1 + b1, stats ----------
__global__ __launch_bounds__(256) void k_gemm1(const float* __restrict__ h,
        const float* __restrict__ aggr, const unsigned short* __restrict__ W1t,
        const float* __restrict__ bias, const float* __restrict__ epsv, int l,
        unsigned short* __restrict__ y1, float* __restrict__ stats, int N) {
    __shared__ uv4 zt[64 * 16];    // 16KB
    __shared__ uv4 wt[256 * 4];    // 16KB
    int tid = threadIdx.x;
    int row0 = blockIdx.x * 64;
    int wave = tid >> 6, lane = tid & 63, lq = lane >> 4, lr = lane & 15;
    float ep = 1.0f + epsv[l];

#pragma unroll
    for (int i = 0; i < 4; ++i) {
        int idx = i * 256 + tid;
        int row = idx >> 4, gz = idx & 15;
        const float* hp = h + (size_t)(row0 + row) * DD + gz * 8;
        const float* ap = aggr + (size_t)(row0 + row) * DD + gz * 8;
        float4 h0 = *(const float4*)hp, h1 = *(const float4*)(hp + 4);
        float4 a0 = *(const float4*)ap, a1 = *(const float4*)(ap + 4);
        float f[8] = {ep * h0.x + a0.x, ep * h0.y + a0.y, ep * h0.z + a0.z, ep * h0.w + a0.w,
                      ep * h1.x + a1.x, ep * h1.y + a1.y, ep * h1.z + a1.z, ep * h1.w + a1.w};
        uv4 p;
#pragma unroll
        for (int j = 0; j < 4; ++j)
            p[j] = (unsigned int)f2bf(f[2 * j]) | ((unsigned int)f2bf(f[2 * j + 1]) << 16);
        zt[row * 16 + (gz ^ (row & 15))] = p;
    }

    fv4 acc[4][4];
#pragma unroll
    for (int m = 0; m < 4; ++m)
#pragma unroll
        for (int nb = 0; nb < 4; ++nb) acc[m][nb] = (fv4){0.f, 0.f, 0.f, 0.f};

    const uv4* wsrc = (const uv4*)W1t + (size_t)l * 4096;
    for (int kc = 0; kc < 4; ++kc) {
        __syncthreads();
#pragma unroll
        for (int i = 0; i < 4; ++i) {
            int g = i * 256 + tid;
            int n = g >> 2, gw = g & 3;
            wt[n * 4 + (gw ^ ((n >> 1) & 3))] = wsrc[(size_t)kc * 1024 + g];
        }
        __syncthreads();
        bfv8 a[4], b[4];
#pragma unroll
        for (int m = 0; m < 4; ++m) {
            int row = m * 16 + lr;
            a[m] = __builtin_bit_cast(bfv8, zt[row * 16 + ((kc * 4 + lq) ^ (row & 15))]);
        }
#pragma unroll
        for (int nb = 0; nb < 4; ++nb) {
            int col = wave * 64 + nb * 16 + lr;
            b[nb] = __builtin_bit_cast(bfv8, wt[col * 4 + (lq ^ ((col >> 1) & 3))]);
        }
#pragma unroll
        for (int m = 0; m < 4; ++m)
#pragma unroll
            for (int nb = 0; nb < 4; ++nb)
                acc[m][nb] = __builtin_amdgcn_mfma_f32_16x16x32_bf16(a[m], b[nb], acc[m][nb], 0, 0, 0);
    }

    float bv[4], s[4], q[4];
#pragma unroll
    for (int nb = 0; nb < 4; ++nb) {
        bv[nb] = bias[wave * 64 + nb * 16 + lr];
        s[nb] = 0.f; q[nb] = 0.f;
    }
#pragma unroll
    for (int m = 0; m < 4; ++m)
#pragma unroll
        for (int nb = 0; nb < 4; ++nb) {
            int col = wave * 64 + nb * 16 + lr;
#pragma unroll
            for (int r = 0; r < 4; ++r) {
                float v = acc[m][nb][r] + bv[nb];
                int row = row0 + m * 16 + lq * 4 + r;
                y1[(size_t)row * HH + col] = f2bf(v);
                s[nb] += v; q[nb] += v * v;
            }
        }
#pragma unroll
    for (int nb = 0; nb < 4; ++nb) {
        s[nb] += __shfl_xor(s[nb], 16); s[nb] += __shfl_xor(s[nb], 32);
        q[nb] += __shfl_xor(q[nb], 16); q[nb] += __shfl_xor(q[nb], 32);
    }
    if (lane < 16) {
#pragma unroll
        for (int nb = 0; nb < 4; ++nb) {
            int col = wave * 64 + nb * 16 + lr;
            atomicAdd(stats + col, s[nb]);
            atomicAdd(stats + HH + col, q[nb]);
        }
    }
}

// ---------- GEMM2 (MFMA): y2 = relu(bn1(y1)) @ W2 + b2, stats ----------
__global__ __launch_bounds__(256) void k_gemm2(const unsigned short* __restrict__ y1,
        const unsigned short* __restrict__ W2t, const float* __restrict__ bias,
        const float* __restrict__ sc1, const float* __restrict__ sh1,
        float* __restrict__ y2, float* __restrict__ stats2, int N) {
    __shared__ uv4 at[64 * 32];    // 32KB
    __shared__ uv4 wt[128 * 4];    // 8KB
    int tid = threadIdx.x;
    int row0 = blockIdx.x * 64;
    int wave = tid >> 6, lane = tid & 63, lq = lane >> 4, lr = lane & 15;

#pragma unroll
    for (int i = 0; i < 8; ++i) {
        int idx = i * 256 + tid;
        int row = idx >> 5, g = idx & 31;
        uv4 raw = *((const uv4*)y1 + (size_t)(row0 + row) * 32 + g);
        float4 sca = *(const float4*)(sc1 + g * 8), scb = *(const float4*)(sc1 + g * 8 + 4);
        float4 sha = *(const float4*)(sh1 + g * 8), shb = *(const float4*)(sh1 + g * 8 + 4);
        float sc[8] = {sca.x, sca.y, sca.z, sca.w, scb.x, scb.y, scb.z, scb.w};
        float sh[8] = {sha.x, sha.y, sha.z, sha.w, shb.x, shb.y, shb.z, shb.w};
        uv4 p;
#pragma unroll
        for (int j = 0; j < 4; ++j) {
            float f0 = fmaxf(bf2f((unsigned short)(raw[j] & 0xFFFFu)) * sc[2 * j] + sh[2 * j], 0.f);
            float f1 = fmaxf(bf2f((unsigned short)(raw[j] >> 16)) * sc[2 * j + 1] + sh[2 * j + 1], 0.f);
            p[j] = (unsigned int)f2bf(f0) | ((unsigned int)f2bf(f1) << 16);
        }
        at[row * 32 + (g ^ (row & 15))] = p;
    }

    fv4 acc[4][2];
#pragma unroll
    for (int m = 0; m < 4; ++m) { acc[m][0] = (fv4){0.f,0.f,0.f,0.f}; acc[m][1] = (fv4){0.f,0.f,0.f,0.f}; }

    const uv4* wbase = (const uv4*)W2t;
    for (int kc = 0; kc < 8; ++kc) {
        __syncthreads();
#pragma unroll
        for (int i = 0; i < 2; ++i) {
            int g = i * 256 + tid;
            int n = g >> 2, gw = g & 3;
            wt[n * 4 + (gw ^ ((n >> 1) & 3))] = wbase[(size_t)kc * 512 + g];
        }
        __syncthreads();
        bfv8 a[4], b[2];
#pragma unroll
        for (int m = 0; m < 4; ++m) {
            int row = m * 16 + lr;
            a[m] = __builtin_bit_cast(bfv8, at[row * 32 + ((kc * 4 + lq) ^ (row & 15))]);
        }
#pragma unroll
        for (int nb = 0; nb < 2; ++nb) {
            int col = wave * 32 + nb * 16 + lr;
            b[nb] = __builtin_bit_cast(bfv8, wt[col * 4 + (lq ^ ((col >> 1) & 3))]);
        }
#pragma unroll
        for (int m = 0; m < 4; ++m)
#pragma unroll
            for (int nb = 0; nb < 2; ++nb)
                acc[m][nb] = __builtin_amdgcn_mfma_f32_16x16x32_bf16(a[m], b[nb], acc[m][nb], 0, 0, 0);
    }

    float bv[2], s[2], q[2];
#pragma unroll
    for (int nb = 0; nb < 2; ++nb) {
        bv[nb] = bias[wave * 32 + nb * 16 + lr];
        s[nb] = 0.f; q[nb] = 0.f;
    }
#pragma unroll
    for (int m = 0; m < 4; ++m)
#pragma unroll
        for (int nb = 0; nb < 2; ++nb) {
            int col = wave * 32 + nb * 16 + lr;
#pragma unroll
            for (int r = 0; r < 4; ++r) {
                float v = acc[m][nb][r] + bv[nb];
                int row = row0 + m * 16 + lq * 4 + r;
                y2[(size_t)row * DD + col] = v;
                s[nb] += v; q[nb] += v * v;
            }
        }
#pragma unroll
    for (int nb = 0; nb < 2; ++nb) {
        s[nb] += __shfl_xor(s[nb], 16); s[nb] += __shfl_xor(s[nb], 32);
        q[nb] += __shfl_xor(q[nb], 16); q[nb] += __shfl_xor(q[nb], 32);
    }
    if (lane < 16) {
#pragma unroll
        for (int nb = 0; nb < 2; ++nb) {
            int col = wave * 32 + nb * 16 + lr;
            atomicAdd(stats2 + col, s[nb]);
            atomicAdd(stats2 + DD + col, q[nb]);
        }
    }
}

// ---------- finalize BN ----------
__global__ void k_fin(const float* __restrict__ stats, const float* __restrict__ g,
        const float* __restrict__ b, float* __restrict__ scale, float* __restrict__ shift,
        int C, float invN) {
    int t = threadIdx.x;
    if (t >= C) return;
    float mu = stats[t] * invN;
    float var = stats[C + t] * invN - mu * mu;
    float rs = rsqrtf(var + 1e-5f);
    float sc = g[t] * rs;
    scale[t] = sc;
    shift[t] = b[t] - mu * sc;
}

// ---------- apply BN2 + relu -> h ----------
__global__ __launch_bounds__(256) void k_bnapply(const float* __restrict__ y2,
        const float* __restrict__ scale, const float* __restrict__ shift,
        float* __restrict__ out, int N) {
    size_t gid = (size_t)blockIdx.x * 256 + threadIdx.x;
    size_t base = gid * 4;
    if (base >= (size_t)N * DD) return;
    int c = (int)(base & (DD - 1));
    float4 v = *(const float4*)(y2 + base);
    float4 s = *(const float4*)(scale + c);
    float4 t = *(const float4*)(shift + c);
    float4 o;
    o.x = fmaxf(v.x * s.x + t.x, 0.f);
    o.y = fmaxf(v.y * s.y + t.y, 0.f);
    o.z = fmaxf(v.z * s.z + t.z, 0.f);
    o.w = fmaxf(v.w * s.w + t.w, 0.f);
    *(float4*)(out + base) = o;
}

extern "C" void kernel_launch(void* const* d_in, const int* in_sizes, int n_in,
                              void* d_out, int out_size, void* d_ws, size_t ws_size,
                              hipStream_t stream) {
    const int* x = (const int*)d_in[0];
    const int* ei = (const int*)d_in[1];
    const int* ea = (const int*)d_in[2];
    const float* atom_emb = (const float*)d_in[3];
    const float* bond_emb = (const float*)d_in[4];
    const float* W1 = (const float*)d_in[5];
    const float* b1 = (const float*)d_in[6];
    const float* bn1_g = (const float*)d_in[7];
    const float* bn1_b = (const float*)d_in[8];
    const float* W2 = (const float*)d_in[9];
    const float* b2 = (const float*)d_in[10];
    const float* epsv = (const float*)d_in[11];
    const float* obn_g = (const float*)d_in[12];
    const float* obn_b = (const float*)d_in[13];
    int N = in_sizes[0] / NF_ATOM;   // 200000 (divisible by 64)
    int E = in_sizes[1] / 2;

    float* h = (float*)d_out;
    char* wsb = (char*)d_ws;
    float* aggr = (float*)wsb;                                         // N*128 f32 (also y2)
    unsigned short* y1bf = (unsigned short*)(wsb + (size_t)N * 512);   // N*256 bf16
    float* st = (float*)(wsb + (size_t)N * 1024);                      // 1536 f32
    unsigned short* w1t = (unsigned short*)((char*)st + 6144);
    unsigned short* w2t = w1t + 163840;
    int* rsarr = (int*)(w2t + 163840);
    int* cur = rsarr + (N + 1);
    int* elist = cur + N;
    int* bsum = elist + E;
    int* boff = bsum + 256;
    float* sum1 = st;
    float* sc1 = st + 512;
    float* sh1 = st + 768;
    float* sum2 = st + 1024;
    float* sc2 = st + 1280;
    float* sh2 = st + 1408;
    float invN = 1.0f / (float)N;
    int nb = (N + 1023) / 1024;

    k_wconv<<<1280, 256, 0, stream>>>(W1, W2, w1t, w2t);
    hipMemsetAsync(cur, 0, (size_t)N * 4, stream);
    k_deg<<<(E + 255) / 256, 256, 0, stream>>>(ei, cur, E);
    k_bsum<<<nb, 256, 0, stream>>>(cur, bsum, N);
    k_bscan<<<1, 256, 0, stream>>>(bsum, boff, nb);
    k_csr<<<nb, 256, 0, stream>>>(cur, boff, rsarr, cur, N, E);
    k_scatter<<<(E + 255) / 256, 256, 0, stream>>>(ei, cur, elist, E);

    k_atom<<<(N * 32 + 255) / 256, 256, 0, stream>>>(x, atom_emb, h, N);
    int gb = N / 64;
    for (int l = 0; l < NLAYER; ++l) {
        hipMemsetAsync(st, 0, 1536 * sizeof(float), stream);
        k_aggr<<<(N * 32 + 255) / 256, 256, 0, stream>>>(rsarr, elist, ei, ea,
                bond_emb + (size_t)l * NF_BOND * 6 * DD, h, aggr, N, E);
        k_gemm1<<<gb, 256, 0, stream>>>(h, aggr, w1t, b1 + l * HH, epsv, l, y1bf, sum1, N);
        k_fin<<<1, 256, 0, stream>>>(sum1, bn1_g + l * HH, bn1_b + l * HH, sc1, sh1, HH, invN);
        k_gemm2<<<gb, 256, 0, stream>>>(y1bf, w2t + (size_t)l * 32768, b2 + l * DD,
                sc1, sh1, aggr, sum2, N);
        k_fin<<<1, 128, 0, stream>>>(sum2, obn_g + l * DD, obn_b + l * DD, sc2, sh2, DD, invN);
        k_bnapply<<<(int)(((size_t)N * DD / 4 + 255) / 256), 256, 0, stream>>>(aggr, sc2, sh2, h, N);
    }
}